// Round 1
// baseline (127.607 us; speedup 1.0000x reference)
//
#include <hip/hip_runtime.h>
#include <cstdint>

// Chamfer distance, B=8, N=M=4096, D=128, f32 in, scalar f32 out.
// R13: latency/occupancy attack. Counters showed all pipes <35% busy with
// LDS 40960B -> 4 blocks/CU needs EXACTLY 160KiB (any reservation -> 3).
// Eliminate cminW (8KB LDS) entirely: wave-level col-min via 2x shfl_xor,
// then device atomicMin on float bits (values are d^2 >= 0 up to rounding;
// later fmaxf(,0) clamp makes int-order-among-negatives harmless). LDS now
// 32KB -> 4 blocks/CU with headroom. Also: B-frag ds_reads hoisted ahead of
// the MFMA cluster + s_setprio(1) around it (T5); rowmin/colmin are single
// [B*N]/[B*M] arrays seeded +INF by pass1, so pass3 shrinks to a 256KB
// streaming sqrt+sum (same per-thread order as before).
// Workspace: xb(8M) yb(8M) x2(128K) y2(128K) rowmin(128K) colmin(128K).

#define B_   8
#define N_   4096
#define M_   4096
#define D_   128
#define TPB  8               // y-tiles (64 cols) per block -> 512-col chunk
#define ROWS_PB 256          // x-rows per block = 4 waves * 64
#define XG   (N_ / ROWS_PB)  // 16 x-groups
#define CHUNKS (M_ / (TPB * 64))   // 8 y-chunks

typedef __bf16 bf16x8 __attribute__((ext_vector_type(8)));
typedef float  f32x4  __attribute__((ext_vector_type(4)));
typedef unsigned int u32;

static __device__ __forceinline__ unsigned short f2bf(float f) {
  unsigned u = __float_as_uint(f);
  u += 0x7FFFu + ((u >> 16) & 1u);   // round-to-nearest-even
  return (unsigned short)(u >> 16);
}

static __device__ __forceinline__ void gld16(void* lds, const void* g) {
  __builtin_amdgcn_global_load_lds(
      (const __attribute__((address_space(1))) void*)g,
      (__attribute__((address_space(3))) void*)lds, 16, 0, 0);
}

// Pass 1: wave handles 2 rows (32 lanes x float4 each). xb = bf16(-2x),
// yb = bf16(y), fp32 norms. Also seeds rowmin/colmin to +INF (one lane/row)
// so pass2 can atomicMin into them (re-seeded every launch -> graph-safe).
__global__ __launch_bounds__(256) void pass1_prep(
    const float* __restrict__ x, const float* __restrict__ y,
    unsigned short* __restrict__ xb, unsigned short* __restrict__ yb,
    float* __restrict__ x2, float* __restrict__ y2,
    float* __restrict__ rowmin, float* __restrict__ colmin)
{
  const int ROWS = B_ * N_;
  int gw   = (blockIdx.x * 256 + threadIdx.x) >> 6;   // wave id
  int lane = threadIdx.x & 63;
  int half = lane >> 5, sub = lane & 31;
  int row2 = gw * 2 + half;                  // 0 .. 2*ROWS-1 (x rows then y rows)
  bool isx = row2 < ROWS;
  const float* src; unsigned short* dst; float* nrm; float* minp; int row;
  if (isx) { src = x; dst = xb; nrm = x2; minp = rowmin; row = row2; }
  else     { src = y; dst = yb; nrm = y2; minp = colmin; row = row2 - ROWS; }
  size_t base = (size_t)row * D_ + sub * 4;
  float4 v = *(const float4*)(src + base);
  float sx = isx ? -2.0f : 1.0f;
  u32 p0 = (u32)f2bf(sx * v.x) | ((u32)f2bf(sx * v.y) << 16);
  u32 p1 = (u32)f2bf(sx * v.z) | ((u32)f2bf(sx * v.w) << 16);
  *(uint2*)(dst + base) = make_uint2(p0, p1);
  float s = v.x * v.x + v.y * v.y + v.z * v.z + v.w * v.w;
  #pragma unroll
  for (int m = 1; m < 32; m <<= 1) s += __shfl_xor(s, m, 64);
  if (sub == 0)      nrm[row]  = s;
  else if (sub == 1) minp[row] = __uint_as_float(0x7F800000u);   // +INF seed
}

// Pass 2: block = 256 x-rows (4 waves x 64 rows = 4 row-tiles of 16), loops
// over TPB y-tiles of 64 cols. y staged by global_load_lds into XOR-swizzled
// LDS (row r, logical 16B-chunk c at physical chunk c^(r&15); 256 B rows).
// Fragment layouts (HW-verified):
//   A/B operand: lane holds elems [row=lane&15][k=(lane>>4)*8 + 0..7]
//   C/D:         lane reg r holds [row=(lane>>4)*4+r][col=lane&15]
// acc init = x2_i, so final a = x2_i - 2<x,y>; s = a + y2_j = d^2.
// Col-min per tile: per-lane min over 16 regs covers this quad's 16 rows of
// the wave; shfl_xor(16),(32) folds the 4 quads -> wave col-min -> atomicMin.
__global__ __launch_bounds__(256) void pass2_tile(
    const unsigned short* __restrict__ xb, const unsigned short* __restrict__ yb,
    const float* __restrict__ x2, const float* __restrict__ y2,
    float* __restrict__ rowmin, float* __restrict__ colmin)
{
  __shared__ unsigned short ys[2 * 8192];    // two 16 KB swizzled y-tiles ONLY

  const int tid  = threadIdx.x;
  const int wave = tid >> 6;                 // 0..3
  const int lane = tid & 63;
  const int quad = lane >> 4;
  const int l15  = lane & 15;

  const int id    = blockIdx.x;        // 0..1023
  const int b     = id & 7;
  const int xg    = (id >> 3) & 15;
  const int chunk = id >> 7;           // 0..7
  const int n0    = xg * ROWS_PB;
  const int mc0   = chunk * (TPB * 64);

  // DMA: 16KB tile, 4 gld16 per lane: instr i covers bytes (wave*4+i)*1024+lane*16.
  int srcoff[4], ldsoff[4];
  #pragma unroll
  for (int i = 0; i < 4; ++i) {
    int p  = (wave * 4 + i) * 1024 + lane * 16;
    int r  = p >> 8;                 // y row 0..63
    int pc = (p >> 4) & 15;          // physical chunk
    int c  = pc ^ (r & 15);          // logical chunk
    srcoff[i] = r * D_ + c * 8;      // elements
    ldsoff[i] = (wave * 4 + i) * 1024;
  }

  // preload tile 0
  {
    const unsigned short* src = yb + ((size_t)b * M_ + mc0) * D_;
    #pragma unroll
    for (int i = 0; i < 4; ++i) gld16((char*)ys + ldsoff[i], src + srcoff[i]);
  }

  // A fragments: direct global->register, rows n0 + wave*64 + rt*16 + l15.
  bf16x8 afrag[4][4];   // [kb][rt]
  const size_t xrow0 = (size_t)b * N_ + n0 + wave * 64;
  #pragma unroll
  for (int kb = 0; kb < 4; ++kb)
    #pragma unroll
    for (int rt = 0; rt < 4; ++rt)
      afrag[kb][rt] = *(const bf16x8*)(xb + (xrow0 + rt * 16 + l15) * D_ + kb * 32 + quad * 8);

  // x2 for this wave's 16 output rows (t-invariant), as f32x4 for acc init
  f32x4 xvv[4];
  #pragma unroll
  for (int rt = 0; rt < 4; ++rt)
    #pragma unroll
    for (int r = 0; r < 4; ++r)
      xvv[rt][r] = x2[(size_t)b * N_ + n0 + wave * 64 + rt * 16 + quad * 4 + r];

  const float FINF = __uint_as_float(0x7F800000u);
  float rmin2[4][4];
  #pragma unroll
  for (int rt = 0; rt < 4; ++rt)
    #pragma unroll
    for (int r = 0; r < 4; ++r) rmin2[rt][r] = FINF;

  #pragma unroll 1
  for (int t = 0; t < TPB; ++t) {
    const int m0 = mc0 + t * 64;
    const int d  = (t & 1) * 16384;    // current buffer byte offset
    __syncthreads();  // drains DMA for buf d (prefetch had a full iteration);
                      // fences prior-buffer reads before overwrite

    if (t + 1 < TPB) {  // prefetch next tile into the other buffer ASAP
      const unsigned short* src = yb + ((size_t)b * M_ + m0 + 64) * D_;
      char* dst = (char*)ys + (16384 - d);
      #pragma unroll
      for (int i = 0; i < 4; ++i) gld16(dst + ldsoff[i], src + srcoff[i]);
    }

    // per-tile y^2: 4 per-lane scalars (16-lane coalesced, quad-broadcast);
    // first use is ct0's epilogue -> latency covered by the MFMA cluster.
    float y2r[4];
    #pragma unroll
    for (int ct = 0; ct < 4; ++ct)
      y2r[ct] = y2[(size_t)b * M_ + m0 + ct * 16 + l15];

    #pragma unroll
    for (int ct = 0; ct < 4; ++ct) {
      // hoisted B-fragment reads (swizzled), then a pure-MFMA cluster
      bf16x8 bfr[4];
      #pragma unroll
      for (int kb = 0; kb < 4; ++kb) {
        const int row = ct * 16 + l15;
        const int pcB = (kb * 4 + quad) ^ l15;   // swizzled chunk
        bfr[kb] = *(const bf16x8*)((const char*)ys + d + row * 256 + pcB * 16);
      }
      f32x4 a[4];
      #pragma unroll
      for (int rt = 0; rt < 4; ++rt) a[rt] = xvv[rt];   // acc init = x2
      __builtin_amdgcn_s_setprio(1);
      #pragma unroll
      for (int kb = 0; kb < 4; ++kb)
        #pragma unroll
        for (int rt = 0; rt < 4; ++rt)
          a[rt] = __builtin_amdgcn_mfma_f32_16x16x32_bf16(afrag[kb][rt], bfr[kb], a[rt], 0, 0, 0);
      __builtin_amdgcn_s_setprio(0);

      // epilogue: s = d^2, row-min partials in-register, col-min via shfl tree
      float yv = y2r[ct];
      float c[4];
      #pragma unroll
      for (int rt = 0; rt < 4; ++rt) {
        float s0 = a[rt][0] + yv; rmin2[rt][0] = fminf(rmin2[rt][0], s0);
        float s1 = a[rt][1] + yv; rmin2[rt][1] = fminf(rmin2[rt][1], s1);
        float s2 = a[rt][2] + yv; rmin2[rt][2] = fminf(rmin2[rt][2], s2);
        float s3 = a[rt][3] + yv; rmin2[rt][3] = fminf(rmin2[rt][3], s3);
        c[rt] = fminf(fminf(s0, s1), fminf(s2, s3));
      }
      float cm = fminf(fminf(c[0], c[1]), fminf(c[2], c[3]));
      cm = fminf(cm, __shfl_xor(cm, 16, 64));   // fold quads 0<->1, 2<->3
      cm = fminf(cm, __shfl_xor(cm, 32, 64));   // fold halves -> wave col-min
      if (quad == 0)
        atomicMin((int*)(colmin + (size_t)b * M_ + m0 + ct * 16 + l15),
                  __float_as_int(cm));
    }
  }

  // Row mins over this chunk: reduce across 16 col-lanes, then atomicMin.
  #pragma unroll
  for (int rt = 0; rt < 4; ++rt) {
    #pragma unroll
    for (int r = 0; r < 4; ++r) {
      float v = rmin2[rt][r];
      v = fminf(v, __shfl_xor(v, 1, 64));
      v = fminf(v, __shfl_xor(v, 2, 64));
      v = fminf(v, __shfl_xor(v, 4, 64));
      v = fminf(v, __shfl_xor(v, 8, 64));
      if (l15 == 0)
        atomicMin((int*)(rowmin + (size_t)b * N_ + n0 + wave * 64 + rt * 16 + quad * 4 + r),
                  __float_as_int(v));
    }
  }
}

// Pass 3: stream the two 128KB min arrays, sqrt, sum, atomicAdd the block's
// contribution to the final scalar (d_out pre-zeroed). Same per-thread
// element order as before (s1 from row mins, s2 from col mins).
__global__ __launch_bounds__(256) void pass3_final(
    const float* __restrict__ rowmin, const float* __restrict__ colmin,
    float* __restrict__ out)
{
  const int BN = B_ * N_;
  float s1 = 0.0f, s2 = 0.0f;
  for (int i = blockIdx.x * 256 + threadIdx.x; i < BN; i += 64 * 256) {
    s1 += sqrtf(fmaxf(rowmin[i], 0.0f));
    s2 += sqrtf(fmaxf(colmin[i], 0.0f));
  }
  float s = s1 + s2;
  #pragma unroll
  for (int m = 1; m < 64; m <<= 1) s += __shfl_xor(s, m, 64);
  __shared__ float r1[4];
  int wave = threadIdx.x >> 6, lane = threadIdx.x & 63;
  if (lane == 0) r1[wave] = s;
  __syncthreads();
  if (threadIdx.x == 0)
    atomicAdd(out, (r1[0] + r1[1] + r1[2] + r1[3]) / (float)(B_ * N_));
}

extern "C" void kernel_launch(void* const* d_in, const int* in_sizes, int n_in,
                              void* d_out, int out_size, void* d_ws, size_t ws_size,
                              hipStream_t stream)
{
  const float* x = (const float*)d_in[0];
  const float* y = (const float*)d_in[1];
  char* ws = (char*)d_ws;

  unsigned short* xb = (unsigned short*)(ws);
  unsigned short* yb = (unsigned short*)(ws + (8u << 20));
  float* x2     = (float*)(ws + (16u << 20));
  float* y2     = (float*)(ws + (16u << 20) + (1u << 17));
  float* rowmin = (float*)(ws + (16u << 20) + (2u << 17));   // B*N floats = 128 KB
  float* colmin = (float*)(ws + (16u << 20) + (3u << 17));   // B*M floats = 128 KB
  float* outf = (float*)d_out;

  hipMemsetAsync(outf, 0, sizeof(float), stream);  // atomicAdd target

  pass1_prep<<<(B_ * N_) / 4, 256, 0, stream>>>(x, y, xb, yb, x2, y2, rowmin, colmin);

  pass2_tile<<<B_ * XG * CHUNKS, 256, 0, stream>>>(xb, yb, x2, y2, rowmin, colmin);

  pass3_final<<<64, 256, 0, stream>>>(rowmin, colmin, outf);
}

// Round 2
// 127.555 us; speedup vs baseline: 1.0004x; 1.0004x over previous
//
#include <hip/hip_runtime.h>
#include <cstdint>

// Chamfer distance, B=8, N=M=4096, D=128, f32 in, scalar f32 out.
// R14: R13 post-mortem showed the regression was device atomics (WRITE_SIZE
// 3MB->12.6MB == 786K atomics x 16B memory-side), stalled at each tile's
// barrier vmcnt(0). Revert to R12's plain-store partials, but keep R13's LDS
// shrink: quads fold in-register (2x shfl_xor), so the cross-wave col-min
// buffer is [2][4][64] floats = 2KB (was 8KB). LDS 34816B -> 4 blocks/CU at
// 139KB (no exact-160KB fit). Keep B-frag hoist + s_setprio around MFMA.
// Workspace: xb(8M) yb(8M) x2(128K) y2(128K) rowpart(1M) colpart(2M).

#define B_   8
#define N_   4096
#define M_   4096
#define D_   128
#define TPB  8               // y-tiles (64 cols) per block -> 512-col chunk
#define ROWS_PB 256          // x-rows per block = 4 waves * 64
#define XG   (N_ / ROWS_PB)  // 16 x-groups
#define CHUNKS (M_ / (TPB * 64))   // 8 y-chunks

typedef __bf16 bf16x8 __attribute__((ext_vector_type(8)));
typedef float  f32x4  __attribute__((ext_vector_type(4)));
typedef unsigned int u32;

static __device__ __forceinline__ unsigned short f2bf(float f) {
  unsigned u = __float_as_uint(f);
  u += 0x7FFFu + ((u >> 16) & 1u);   // round-to-nearest-even
  return (unsigned short)(u >> 16);
}

static __device__ __forceinline__ void gld16(void* lds, const void* g) {
  __builtin_amdgcn_global_load_lds(
      (const __attribute__((address_space(1))) void*)g,
      (__attribute__((address_space(3))) void*)lds, 16, 0, 0);
}

// Pass 1: wave handles 2 rows (32 lanes x float4 each). xb = bf16(-2x),
// yb = bf16(y), fp32 norms.
__global__ __launch_bounds__(256) void pass1_prep(
    const float* __restrict__ x, const float* __restrict__ y,
    unsigned short* __restrict__ xb, unsigned short* __restrict__ yb,
    float* __restrict__ x2, float* __restrict__ y2)
{
  const int ROWS = B_ * N_;
  int gw   = (blockIdx.x * 256 + threadIdx.x) >> 6;   // wave id
  int lane = threadIdx.x & 63;
  int half = lane >> 5, sub = lane & 31;
  int row2 = gw * 2 + half;                  // 0 .. 2*ROWS-1 (x rows then y rows)
  bool isx = row2 < ROWS;
  const float* src; unsigned short* dst; float* nrm; int row;
  if (isx) { src = x; dst = xb; nrm = x2; row = row2; }
  else     { src = y; dst = yb; nrm = y2; row = row2 - ROWS; }
  size_t base = (size_t)row * D_ + sub * 4;
  float4 v = *(const float4*)(src + base);
  float sx = isx ? -2.0f : 1.0f;
  u32 p0 = (u32)f2bf(sx * v.x) | ((u32)f2bf(sx * v.y) << 16);
  u32 p1 = (u32)f2bf(sx * v.z) | ((u32)f2bf(sx * v.w) << 16);
  *(uint2*)(dst + base) = make_uint2(p0, p1);
  float s = v.x * v.x + v.y * v.y + v.z * v.z + v.w * v.w;
  #pragma unroll
  for (int m = 1; m < 32; m <<= 1) s += __shfl_xor(s, m, 64);
  if (sub == 0) nrm[row] = s;
}

// Pass 2: block = 256 x-rows (4 waves x 64 rows = 4 row-tiles of 16), loops
// over TPB y-tiles of 64 cols. y staged by global_load_lds into XOR-swizzled
// LDS (row r, logical 16B-chunk c at physical chunk c^(r&15); 256 B rows).
// Fragment layouts (HW-verified):
//   A/B operand: lane holds elems [row=lane&15][k=(lane>>4)*8 + 0..7]
//   C/D:         lane reg r holds [row=(lane>>4)*4+r][col=lane&15]
// acc init = x2_i, so final a = x2_i - 2<x,y>; s = a + y2_j = d^2.
// Col-min per tile: per-lane min over 16 regs covers this quad's 16 rows;
// shfl_xor(16),(32) folds quads -> wave col-min -> 2KB dbuf LDS -> flush
// (min over 4 waves) to per-xg colpart slice with a plain coalesced store.
__global__ __launch_bounds__(256) void pass2_tile(
    const unsigned short* __restrict__ xb, const unsigned short* __restrict__ yb,
    const float* __restrict__ x2, const float* __restrict__ y2,
    float* __restrict__ rowpart, float* __restrict__ colpart)
{
  __shared__ unsigned short ys[2 * 8192];    // two 16 KB swizzled y-tiles
  __shared__ float cminW[2][4][64];          // dbuf per-wave col-min (2 KB)

  const int tid  = threadIdx.x;
  const int wave = tid >> 6;                 // 0..3
  const int lane = tid & 63;
  const int quad = lane >> 4;
  const int l15  = lane & 15;

  const int id    = blockIdx.x;        // 0..1023
  const int b     = id & 7;
  const int xg    = (id >> 3) & 15;
  const int chunk = id >> 7;           // 0..7
  const int n0    = xg * ROWS_PB;
  const int mc0   = chunk * (TPB * 64);

  // DMA: 16KB tile, 4 gld16 per lane: instr i covers bytes (wave*4+i)*1024+lane*16.
  int srcoff[4], ldsoff[4];
  #pragma unroll
  for (int i = 0; i < 4; ++i) {
    int p  = (wave * 4 + i) * 1024 + lane * 16;
    int r  = p >> 8;                 // y row 0..63
    int pc = (p >> 4) & 15;          // physical chunk
    int c  = pc ^ (r & 15);          // logical chunk
    srcoff[i] = r * D_ + c * 8;      // elements
    ldsoff[i] = (wave * 4 + i) * 1024;
  }

  // preload tile 0
  {
    const unsigned short* src = yb + ((size_t)b * M_ + mc0) * D_;
    #pragma unroll
    for (int i = 0; i < 4; ++i) gld16((char*)ys + ldsoff[i], src + srcoff[i]);
  }

  // A fragments: direct global->register, rows n0 + wave*64 + rt*16 + l15.
  bf16x8 afrag[4][4];   // [kb][rt]
  const size_t xrow0 = (size_t)b * N_ + n0 + wave * 64;
  #pragma unroll
  for (int kb = 0; kb < 4; ++kb)
    #pragma unroll
    for (int rt = 0; rt < 4; ++rt)
      afrag[kb][rt] = *(const bf16x8*)(xb + (xrow0 + rt * 16 + l15) * D_ + kb * 32 + quad * 8);

  // x2 for this wave's 16 output rows (t-invariant), as f32x4 for acc init
  f32x4 xvv[4];
  #pragma unroll
  for (int rt = 0; rt < 4; ++rt)
    #pragma unroll
    for (int r = 0; r < 4; ++r)
      xvv[rt][r] = x2[(size_t)b * N_ + n0 + wave * 64 + rt * 16 + quad * 4 + r];

  const float FINF = __uint_as_float(0x7F800000u);
  float rmin2[4][4];
  #pragma unroll
  for (int rt = 0; rt < 4; ++rt)
    #pragma unroll
    for (int r = 0; r < 4; ++r) rmin2[rt][r] = FINF;

  #pragma unroll 1
  for (int t = 0; t < TPB; ++t) {
    const int m0 = mc0 + t * 64;
    const int d  = (t & 1) * 16384;    // current buffer byte offset
    __syncthreads();  // drains DMA for buf d (prefetch had a full iteration);
                      // fences prior-buffer reads and cminW[(t-1)&1] writes

    if (t + 1 < TPB) {  // prefetch next tile into the other buffer ASAP
      const unsigned short* src = yb + ((size_t)b * M_ + m0 + 64) * D_;
      char* dst = (char*)ys + (16384 - d);
      #pragma unroll
      for (int i = 0; i < 4; ++i) gld16(dst + ldsoff[i], src + srcoff[i]);
    }

    // Flush previous tile's column mins (other cminW buffer -> no race):
    // col j's min = min over the 4 per-wave partials.
    if (t > 0 && tid < 64) {
      const float* cb = &cminW[(t - 1) & 1][0][0];
      float v = cb[tid];
      #pragma unroll
      for (int w = 1; w < 4; ++w) v = fminf(v, cb[w * 64 + tid]);
      colpart[(size_t)xg * (B_ * M_) + (size_t)b * M_ + (m0 - 64) + tid] = v;
    }

    // per-tile y^2: 4 per-lane scalars (16-lane coalesced, quad-broadcast);
    // first use is ct0's epilogue -> latency covered by the MFMA cluster.
    float y2r[4];
    #pragma unroll
    for (int ct = 0; ct < 4; ++ct)
      y2r[ct] = y2[(size_t)b * M_ + m0 + ct * 16 + l15];

    #pragma unroll
    for (int ct = 0; ct < 4; ++ct) {
      // hoisted B-fragment reads (swizzled), then a pure-MFMA cluster
      bf16x8 bfr[4];
      #pragma unroll
      for (int kb = 0; kb < 4; ++kb) {
        const int row = ct * 16 + l15;
        const int pcB = (kb * 4 + quad) ^ l15;   // swizzled chunk
        bfr[kb] = *(const bf16x8*)((const char*)ys + d + row * 256 + pcB * 16);
      }
      f32x4 a[4];
      #pragma unroll
      for (int rt = 0; rt < 4; ++rt) a[rt] = xvv[rt];   // acc init = x2
      __builtin_amdgcn_s_setprio(1);
      #pragma unroll
      for (int kb = 0; kb < 4; ++kb)
        #pragma unroll
        for (int rt = 0; rt < 4; ++rt)
          a[rt] = __builtin_amdgcn_mfma_f32_16x16x32_bf16(afrag[kb][rt], bfr[kb], a[rt], 0, 0, 0);
      __builtin_amdgcn_s_setprio(0);

      // epilogue: s = d^2, row-min partials in-register, col-min via shfl tree
      float yv = y2r[ct];
      float c[4];
      #pragma unroll
      for (int rt = 0; rt < 4; ++rt) {
        float s0 = a[rt][0] + yv; rmin2[rt][0] = fminf(rmin2[rt][0], s0);
        float s1 = a[rt][1] + yv; rmin2[rt][1] = fminf(rmin2[rt][1], s1);
        float s2 = a[rt][2] + yv; rmin2[rt][2] = fminf(rmin2[rt][2], s2);
        float s3 = a[rt][3] + yv; rmin2[rt][3] = fminf(rmin2[rt][3], s3);
        c[rt] = fminf(fminf(s0, s1), fminf(s2, s3));
      }
      float cm = fminf(fminf(c[0], c[1]), fminf(c[2], c[3]));
      cm = fminf(cm, __shfl_xor(cm, 16, 64));   // fold quads 0<->1, 2<->3
      cm = fminf(cm, __shfl_xor(cm, 32, 64));   // fold halves -> wave col-min
      if (quad == 0)
        cminW[t & 1][wave][ct * 16 + l15] = cm;
    }
  }

  __syncthreads();  // final tile's cminW writes visible
  if (tid < 64) {
    const float* cb = &cminW[(TPB - 1) & 1][0][0];
    float v = cb[tid];
    #pragma unroll
    for (int w = 1; w < 4; ++w) v = fminf(v, cb[w * 64 + tid]);
    colpart[(size_t)xg * (B_ * M_) + (size_t)b * M_ + (mc0 + (TPB - 1) * 64) + tid] = v;
  }

  // Row mins over this chunk: reduce across 16 col-lanes (once, at the end).
  #pragma unroll
  for (int rt = 0; rt < 4; ++rt) {
    #pragma unroll
    for (int r = 0; r < 4; ++r) {
      float v = rmin2[rt][r];
      v = fminf(v, __shfl_xor(v, 1, 64));
      v = fminf(v, __shfl_xor(v, 2, 64));
      v = fminf(v, __shfl_xor(v, 4, 64));
      v = fminf(v, __shfl_xor(v, 8, 64));
      if (l15 == 0)
        rowpart[(size_t)chunk * (B_ * N_) + (size_t)b * N_ + n0 + wave * 64 + rt * 16 + quad * 4 + r] = v;
    }
  }
}

// Pass 3: reduce partials (min over chunks/x-groups), sqrt, sum, atomicAdd
// the block's contribution to the final scalar (d_out pre-zeroed).
__global__ __launch_bounds__(256) void pass3_final(
    const float* __restrict__ rowpart, const float* __restrict__ colpart,
    float* __restrict__ out)
{
  const int BN = B_ * N_;
  float s1 = 0.0f, s2 = 0.0f;
  for (int i = blockIdx.x * 256 + threadIdx.x; i < BN; i += 64 * 256) {
    float r = rowpart[i];
    #pragma unroll
    for (int c = 1; c < CHUNKS; ++c) r = fminf(r, rowpart[c * BN + i]);
    s1 += sqrtf(fmaxf(r, 0.0f));
    float m = colpart[i];
    #pragma unroll
    for (int g = 1; g < XG; ++g) m = fminf(m, colpart[g * BN + i]);
    s2 += sqrtf(fmaxf(m, 0.0f));
  }
  float s = s1 + s2;
  #pragma unroll
  for (int m = 1; m < 64; m <<= 1) s += __shfl_xor(s, m, 64);
  __shared__ float r1[4];
  int wave = threadIdx.x >> 6, lane = threadIdx.x & 63;
  if (lane == 0) r1[wave] = s;
  __syncthreads();
  if (threadIdx.x == 0)
    atomicAdd(out, (r1[0] + r1[1] + r1[2] + r1[3]) / (float)(B_ * N_));
}

extern "C" void kernel_launch(void* const* d_in, const int* in_sizes, int n_in,
                              void* d_out, int out_size, void* d_ws, size_t ws_size,
                              hipStream_t stream)
{
  const float* x = (const float*)d_in[0];
  const float* y = (const float*)d_in[1];
  char* ws = (char*)d_ws;

  unsigned short* xb = (unsigned short*)(ws);
  unsigned short* yb = (unsigned short*)(ws + (8u << 20));
  float* x2      = (float*)(ws + (16u << 20));
  float* y2      = (float*)(ws + (16u << 20) + (1u << 17));
  float* rowpart = (float*)(ws + (16u << 20) + (2u << 17));    // 8*B*N floats = 1 MB
  float* colpart = (float*)(ws + (16u << 20) + (10u << 17));   // 16*B*M floats = 2 MB
  float* outf = (float*)d_out;

  hipMemsetAsync(outf, 0, sizeof(float), stream);  // atomicAdd target

  pass1_prep<<<(B_ * N_) / 4, 256, 0, stream>>>(x, y, xb, yb, x2, y2);

  pass2_tile<<<B_ * XG * CHUNKS, 256, 0, stream>>>(xb, yb, x2, y2, rowpart, colpart);

  pass3_final<<<64, 256, 0, stream>>>(rowpart, colpart, outf);
}